// Round 10
// baseline (521.925 us; speedup 1.0000x reference)
//
#include <hip/hip_runtime.h>

typedef __attribute__((ext_vector_type(4))) float f32x4;
typedef __attribute__((ext_vector_type(8))) short s16x8;

__device__ __forceinline__ ushort f2bf(float f) {
  union { float f; uint u; } v; v.f = f;
  uint r = v.u + 0x7fffu + ((v.u >> 16) & 1u);
  return (ushort)(r >> 16);
}

__device__ __forceinline__ void glds16(const void* g, void* l) {
  __builtin_amdgcn_global_load_lds(
      (const __attribute__((address_space(1))) uint*)g,
      (__attribute__((address_space(3))) uint*)l, 16, 0, 0);
}

// swizzled index into a [rows][256] bf16 tile (16B-chunk XOR by row&7)
__device__ __forceinline__ int asidx(int row, int col) {
  return row*256 + ((((col>>3) ^ (row & 7)))<<3) + (col&7);
}
// swizzled index into a [rows][32] bf16 scratch tile
__device__ __forceinline__ int scridx(int row, int col) {
  return row*32 + ((((col>>3) ^ ((row>>2)&3)))<<3) + (col&7);
}
// fp32 [16][32] per-wave staging: XOR bits 2-4 (float4-safe bijection)
__device__ __forceinline__ int scrfidx(int row, int c) {
  return row*32 + (c ^ ((row & 7) << 2));
}

struct WSrc { const float* p[8]; };

// fp32 [*,256,256] (f-major) -> bf16 WT[n=g][k=f] with the chunk XOR swizzle
// baked in, so a LINEAR global_load_lds stage yields the swizzled LDS layout.
__global__ __launch_bounds__(256) void prep_weights(WSrc s, ushort* wq, ushort* wo) {
  int mm = blockIdx.x >> 6;          // 0..15: axis*4 + {0,1,2:qkv mats, 3:wo}
  int t  = blockIdx.x & 63;
  int a = mm >> 2, sub = mm & 3;
  const float* src = (sub < 3) ? (s.p[a*2] + sub*65536) : s.p[a*2+1];
  ushort*      dst = (sub < 3) ? (wq + (a*3 + sub)*65536) : (wo + a*65536);
  int gt = (t >> 3) * 32, ft = (t & 7) * 32;
  __shared__ float tile[32][33];
  int lx = threadIdx.x & 31, ly = threadIdx.x >> 5;
#pragma unroll
  for (int i = 0; i < 4; i++)
    tile[ly + i*8][lx] = src[(ft + ly + i*8)*256 + gt + lx];
  __syncthreads();
#pragma unroll
  for (int i = 0; i < 4; i++) {
    int n = gt + ly + i*8, col = ft + lx;
    dst[asidx(n, col)] = f2bf(tile[lx][ly + i*8]);
  }
}

// 128-token blocks (512 of them)
template<int AXIS>
__device__ __forceinline__ int token_index(int blk, int row) {
  if (AXIS == 0) {                       // temporal: 16 seqs/block of len 8
    int seq = blk*16 + (row >> 3);
    int t = row & 7;
    int b = seq >> 12, n = seq & 4095;
    return (b*8 + t)*4096 + n;
  } else {                               // spatial: 8 seqs/block of len 16
    int sid = blk*8 + (row >> 4);
    int bt = sid >> 8, lo = sid & 255, r = row & 15;
    if (AXIS == 1) return bt*4096 + r*256 + lo;
    if (AXIS == 2) { int dd = lo >> 4, ww = lo & 15; return bt*4096 + dd*256 + r*16 + ww; }
    return bt*4096 + lo*16 + r;
  }
}

// LDS-write publication fence (raw s_barrier does NOT drain ds ops).
#define PUB_BARRIER() do { \
    __builtin_amdgcn_sched_barrier(0); \
    asm volatile("s_waitcnt lgkmcnt(0)" ::: "memory"); \
    __builtin_amdgcn_sched_barrier(0); \
    __builtin_amdgcn_s_barrier(); \
    __builtin_amdgcn_sched_barrier(0); } while (0)

template<int AXIS>
__global__ __launch_bounds__(512, 4) void axial_pass(
    const float* __restrict__ x0, const ushort* __restrict__ xb,
    const ushort* __restrict__ wqkvT, const float* __restrict__ bqkv,
    const ushort* __restrict__ woT, const float* __restrict__ bo,
    float* __restrict__ out, ushort* __restrict__ x1b) {

  // 56 KB: Wbuf 2x16KB | QKP 8 packets x (Q 1KB + K/P 1KB) | Vt 4 pairs x 2KB
  __shared__ ushort smem[28672];
  ushort* Wb0 = smem;
  ushort* Wb1 = smem + 8192;
  ushort* QKP = smem + 16384;    // packet p at +p*1024: Q [0,512) KP [512,1024)
  ushort* Vt  = smem + 24576;    // pair p at +p*1024: [32 d][32 t'] (t' = packet-interleaved)

  const int tid = threadIdx.x, blk = blockIdx.x;
  const int wv = tid >> 6, lane = tid & 63, llo = lane & 15, lhi = lane >> 4;
  const int rg = wv >> 1, ch = wv & 1;   // row-group (32 rows), n-half
  const f32x4 fzero = {0.f, 0.f, 0.f, 0.f};

  auto issue_stage = [&](int s) {
    const ushort* src = (s < 24) ? (wqkvT + (s % 3)*65536 + (s / 3)*8192)
                                 : (woT + (s - 24)*8192);
    const ushort* g = src + wv*1024 + lane*8;
    ushort* l = ((s & 1) ? Wb1 : Wb0) + wv*1024;
    glds16(g, l);
    glds16(g + 512, l + 512);
  };

  // Single barrier per stage, collective order (round-7-proven): drain own
  // vmcnt+lgkm BEFORE the barrier, issue the next stage AFTER it.
#define STAGE_SYNC(sn) do { \
    __builtin_amdgcn_sched_barrier(0); \
    asm volatile("s_waitcnt vmcnt(0) lgkmcnt(0)" ::: "memory"); \
    __builtin_amdgcn_sched_barrier(0); \
    __builtin_amdgcn_s_barrier(); \
    __builtin_amdgcn_sched_barrier(0); \
    if ((sn) < 32) issue_stage(sn); \
  } while (0)

  issue_stage(0);   // stage-0 weights load under the af loads below

  // ---- A-fragments straight from global: 32 rows/wave (2 groups of 16) ----
  s16x8 af[2][8];
#pragma unroll
  for (int g = 0; g < 2; g++) {
    int row = rg*32 + g*16 + llo;
    int tok = token_index<AXIS>(blk, row);
    if (AXIS == 0) {
      const float* xp = x0 + (size_t)tok*256;
#pragma unroll
      for (int ks = 0; ks < 8; ks++) {
        float4 a = *(const float4*)(xp + ks*32 + lhi*8);
        float4 b = *(const float4*)(xp + ks*32 + lhi*8 + 4);
        s16x8 o;
        o[0] = (short)f2bf(a.x); o[1] = (short)f2bf(a.y);
        o[2] = (short)f2bf(a.z); o[3] = (short)f2bf(a.w);
        o[4] = (short)f2bf(b.x); o[5] = (short)f2bf(b.y);
        o[6] = (short)f2bf(b.z); o[7] = (short)f2bf(b.w);
        af[g][ks] = o;
      }
    } else {
      const ushort* xp = xb + (size_t)tok*256;
#pragma unroll
      for (int ks = 0; ks < 8; ks++)
        af[g][ks] = *(const s16x8*)(xp + ks*32 + lhi*8);
    }
  }

  s16x8 af_o[8];   // per-head attn-out A-fragments (own packet), static-indexed

  // ================= head loop (fully unrolled: af_o[h] static) =============
#pragma unroll
  for (int h = 0; h < 8; h++) {
    // ---- Q (stage 3h): 16 MFMA, one B-read feeds both row-groups ----
    STAGE_SYNC(3*h + 1);
    {
      const ushort* buf = ((3*h) & 1) ? Wb1 : Wb0;
      f32x4 c0 = fzero, c1 = fzero;
      __builtin_amdgcn_s_setprio(1);
#pragma unroll
      for (int ks = 0; ks < 8; ks++) {
        s16x8 bv = *(const s16x8*)(buf + asidx(ch*16 + llo, (ks*4 + lhi)*8));
        c0 = __builtin_amdgcn_mfma_f32_16x16x32_bf16(af[0][ks], bv, c0, 0, 0, 0);
        c1 = __builtin_amdgcn_mfma_f32_16x16x32_bf16(af[1][ks], bv, c1, 0, 0, 0);
      }
      __builtin_amdgcn_s_setprio(0);
      float bi = bqkv[h*32 + ch*16 + llo];
      ushort* q0 = QKP + (rg*2 + 0)*1024;
      ushort* q1 = QKP + (rg*2 + 1)*1024;
#pragma unroll
      for (int r = 0; r < 4; r++) {
        q0[scridx(lhi*4 + r, ch*16 + llo)] = f2bf(c0[r] + bi);
        q1[scridx(lhi*4 + r, ch*16 + llo)] = f2bf(c1[r] + bi);
      }
    }
    // ---- K (stage 3h+1) ----
    STAGE_SYNC(3*h + 2);
    {
      const ushort* buf = ((3*h + 1) & 1) ? Wb1 : Wb0;
      f32x4 c0 = fzero, c1 = fzero;
      __builtin_amdgcn_s_setprio(1);
#pragma unroll
      for (int ks = 0; ks < 8; ks++) {
        s16x8 bv = *(const s16x8*)(buf + asidx(ch*16 + llo, (ks*4 + lhi)*8));
        c0 = __builtin_amdgcn_mfma_f32_16x16x32_bf16(af[0][ks], bv, c0, 0, 0, 0);
        c1 = __builtin_amdgcn_mfma_f32_16x16x32_bf16(af[1][ks], bv, c1, 0, 0, 0);
      }
      __builtin_amdgcn_s_setprio(0);
      float bi = bqkv[256 + h*32 + ch*16 + llo];
      ushort* k0 = QKP + (rg*2 + 0)*1024 + 512;
      ushort* k1 = QKP + (rg*2 + 1)*1024 + 512;
#pragma unroll
      for (int r = 0; r < 4; r++) {
        k0[scridx(lhi*4 + r, ch*16 + llo)] = f2bf(c0[r] + bi);
        k1[scridx(lhi*4 + r, ch*16 + llo)] = f2bf(c1[r] + bi);
      }
    }
    // ---- V (stage 3h+2), stored transposed into the pair tile ----
    STAGE_SYNC(3*h + 3);
    {
      const ushort* buf = ((3*h + 2) & 1) ? Wb1 : Wb0;
      f32x4 c0 = fzero, c1 = fzero;
      __builtin_amdgcn_s_setprio(1);
#pragma unroll
      for (int ks = 0; ks < 8; ks++) {
        s16x8 bv = *(const s16x8*)(buf + asidx(ch*16 + llo, (ks*4 + lhi)*8));
        c0 = __builtin_amdgcn_mfma_f32_16x16x32_bf16(af[0][ks], bv, c0, 0, 0, 0);
        c1 = __builtin_amdgcn_mfma_f32_16x16x32_bf16(af[1][ks], bv, c1, 0, 0, 0);
      }
      __builtin_amdgcn_s_setprio(0);
      float bi = bqkv[512 + h*32 + ch*16 + llo];
      ushort* vt = Vt + rg*1024;      // [d 32][t' 32]; packet g at cols g*16..
#pragma unroll
      for (int r = 0; r < 4; r++) {
        vt[scridx(ch*16 + llo, 0*16 + lhi*4 + r)] = f2bf(c0[r] + bi);
        vt[scridx(ch*16 + llo, 1*16 + lhi*4 + r)] = f2bf(c1[r] + bi);
      }
    }
    PUB_BARRIER();   // Q,K,V for all packets published

    // ---- attention: wave owns packet wv; all subsequent LDS same-wave ----
    {
      ushort* myQ  = QKP + wv*1024;
      ushort* myKP = myQ + 512;
      const ushort* myVt = Vt + (wv >> 1)*1024;
      const int mh = wv & 1;           // my column-half in the pair tile
      s16x8 aq = *(const s16x8*)(myQ  + scridx(llo, lhi*8));
      s16x8 bk = *(const s16x8*)(myKP + scridx(llo, lhi*8));
      f32x4 sc = __builtin_amdgcn_mfma_f32_16x16x32_bf16(aq, bk, fzero, 0, 0, 0);
#pragma unroll
      for (int r = 0; r < 4; r++) {
        float sv = sc[r] * 0.17677669529663689f;
        if (AXIS == 0) {   // packet = two length-8 t-seqs: block-diagonal mask
          int srow = lhi*4 + r;
          if ((srow >> 3) != (llo >> 3)) sv = -1e30f;
        }
        float mx = sv;
        mx = fmaxf(mx, __shfl_xor(mx, 1));
        mx = fmaxf(mx, __shfl_xor(mx, 2));
        mx = fmaxf(mx, __shfl_xor(mx, 4));
        mx = fmaxf(mx, __shfl_xor(mx, 8));
        float e = __expf(sv - mx);
        float sm = e;
        sm += __shfl_xor(sm, 1);
        sm += __shfl_xor(sm, 2);
        sm += __shfl_xor(sm, 4);
        sm += __shfl_xor(sm, 8);
        // P over K (same-wave): real at my half, zero at the other half so
        // the k=32 PV over the shared pair tile drops the buddy packet.
        myKP[scridx(lhi*4 + r, mh*16 + llo)]       = f2bf(e * __builtin_amdgcn_rcpf(sm));
        myKP[scridx(lhi*4 + r, (1 - mh)*16 + llo)] = 0;
      }
      s16x8 ap  = *(const s16x8*)(myKP + scridx(llo, lhi*8));
      s16x8 bv0 = *(const s16x8*)(myVt + scridx(llo, lhi*8));
      s16x8 bv1 = *(const s16x8*)(myVt + scridx(16 + llo, lhi*8));
      f32x4 o0 = __builtin_amdgcn_mfma_f32_16x16x32_bf16(ap, bv0, fzero, 0, 0, 0);
      f32x4 o1 = __builtin_amdgcn_mfma_f32_16x16x32_bf16(ap, bv1, fzero, 0, 0, 0);
      // transpose o through the dead Q-area (same-wave), harvest A-fragment
#pragma unroll
      for (int r = 0; r < 4; r++) {
        myQ[scridx(lhi*4 + r, llo)]      = f2bf(o0[r]);
        myQ[scridx(lhi*4 + r, 16 + llo)] = f2bf(o1[r]);
      }
      af_o[h] = *(const s16x8*)(myQ + scridx(llo, lhi*8));
    }
  }

  // ================= out-proj: stages 24..31, A = af_o (own packet) =========
#pragma unroll 1
  for (int st = 0; st < 8; st++) {
    STAGE_SYNC(25 + st);
    const ushort* buf = (st & 1) ? Wb1 : Wb0;   // stage 24+st, 24 is even
    f32x4 c0 = fzero, c1 = fzero;
    __builtin_amdgcn_s_setprio(1);
#pragma unroll
    for (int ks = 0; ks < 8; ks++) {
      s16x8 b0 = *(const s16x8*)(buf + asidx(llo,      (ks*4 + lhi)*8));
      s16x8 b1 = *(const s16x8*)(buf + asidx(16 + llo, (ks*4 + lhi)*8));
      c0 = __builtin_amdgcn_mfma_f32_16x16x32_bf16(af_o[ks], b0, c0, 0, 0, 0);
      c1 = __builtin_amdgcn_mfma_f32_16x16x32_bf16(af_o[ks], b1, c1, 0, 0, 0);
    }
    __builtin_amdgcn_s_setprio(0);

    // transpose 16x32 fp32 through own scratch (same-wave), vector RMW
    float* Scf = (float*)(QKP + wv*1024);
#pragma unroll
    for (int r = 0; r < 4; r++) {
      Scf[scrfidx(lhi*4 + r, llo)]      = c0[r];
      Scf[scrfidx(lhi*4 + r, 16 + llo)] = c1[r];
    }
    {
      int row = lane >> 2, cb = (lane & 3)*8;
      float4 fa = *(const float4*)&Scf[scrfidx(row, cb)];
      float4 fb = *(const float4*)&Scf[scrfidx(row, cb + 4)];
      int col = st*32 + cb;
      int tok = token_index<AXIS>(blk, wv*16 + row);
      size_t base = (size_t)tok*256;
      float4 ba = *(const float4*)&bo[col];
      float4 bb4 = *(const float4*)&bo[col + 4];
      fa.x += ba.x; fa.y += ba.y; fa.z += ba.z; fa.w += ba.w;
      fb.x += bb4.x; fb.y += bb4.y; fb.z += bb4.z; fb.w += bb4.w;
      if (AXIS == 0) {
        float4 xa = *(const float4*)&x0[base + col];
        float4 xb4 = *(const float4*)&x0[base + col + 4];
        fa.x += xa.x; fa.y += xa.y; fa.z += xa.z; fa.w += xa.w;
        fb.x += xb4.x; fb.y += xb4.y; fb.z += xb4.z; fb.w += xb4.w;
        *(float4*)&out[base + col]     = fa;
        *(float4*)&out[base + col + 4] = fb;
        s16x8 p;
        p[0] = (short)f2bf(fa.x); p[1] = (short)f2bf(fa.y);
        p[2] = (short)f2bf(fa.z); p[3] = (short)f2bf(fa.w);
        p[4] = (short)f2bf(fb.x); p[5] = (short)f2bf(fb.y);
        p[6] = (short)f2bf(fb.z); p[7] = (short)f2bf(fb.w);
        *(s16x8*)&x1b[base + col] = p;
      } else {
        float4 oa = *(float4*)&out[base + col];
        float4 ob = *(float4*)&out[base + col + 4];
        oa.x += fa.x; oa.y += fa.y; oa.z += fa.z; oa.w += fa.w;
        ob.x += fb.x; ob.y += fb.y; ob.z += fb.z; ob.w += fb.w;
        *(float4*)&out[base + col]     = oa;
        *(float4*)&out[base + col + 4] = ob;
      }
    }
  }
#undef STAGE_SYNC
}

extern "C" void kernel_launch(void* const* d_in, const int* in_sizes, int n_in,
                              void* d_out, int out_size, void* d_ws, size_t ws_size,
                              hipStream_t stream) {
  const float* x = (const float*)d_in[0];
  ushort* wq  = (ushort*)d_ws;                 // 4*3*65536 bf16
  ushort* wo  = wq + 4*3*65536;                // 4*65536 bf16
  ushort* x1b = wo + 4*65536;                  // 65536*256 bf16
  float* out = (float*)d_out;

  WSrc wsrc;
  wsrc.p[0] = (const float*)d_in[1];  wsrc.p[1] = (const float*)d_in[3];
  wsrc.p[2] = (const float*)d_in[5];  wsrc.p[3] = (const float*)d_in[7];
  wsrc.p[4] = (const float*)d_in[9];  wsrc.p[5] = (const float*)d_in[11];
  wsrc.p[6] = (const float*)d_in[13]; wsrc.p[7] = (const float*)d_in[15];
  prep_weights<<<dim3(1024), dim3(256), 0, stream>>>(wsrc, wq, wo);

  const float* bq_t = (const float*)d_in[2];  const float* bo_t = (const float*)d_in[4];
  const float* bq_d = (const float*)d_in[6];  const float* bo_d = (const float*)d_in[8];
  const float* bq_h = (const float*)d_in[10]; const float* bo_h = (const float*)d_in[12];
  const float* bq_w = (const float*)d_in[14]; const float* bo_w = (const float*)d_in[16];

  axial_pass<0><<<dim3(512), dim3(512), 0, stream>>>(x, nullptr, wq + 0*3*65536, bq_t, wo + 0*65536, bo_t, out, x1b);
  axial_pass<1><<<dim3(512), dim3(512), 0, stream>>>(nullptr, x1b, wq + 1*3*65536, bq_d, wo + 1*65536, bo_d, out, nullptr);
  axial_pass<2><<<dim3(512), dim3(512), 0, stream>>>(nullptr, x1b, wq + 2*3*65536, bq_h, wo + 2*65536, bo_h, out, nullptr);
  axial_pass<3><<<dim3(512), dim3(512), 0, stream>>>(nullptr, x1b, wq + 3*3*65536, bq_w, wo + 3*65536, bo_w, out, nullptr);
}

// Round 11
// 462.628 us; speedup vs baseline: 1.1282x; 1.1282x over previous
//
#include <hip/hip_runtime.h>

typedef __attribute__((ext_vector_type(4))) float f32x4;
typedef __attribute__((ext_vector_type(8))) short s16x8;

__device__ __forceinline__ ushort f2bf(float f) {
  union { float f; uint u; } v; v.f = f;
  uint r = v.u + 0x7fffu + ((v.u >> 16) & 1u);
  return (ushort)(r >> 16);
}

__device__ __forceinline__ void glds16(const void* g, void* l) {
  __builtin_amdgcn_global_load_lds(
      (const __attribute__((address_space(1))) uint*)g,
      (__attribute__((address_space(3))) uint*)l, 16, 0, 0);
}

// swizzled index into a [rows][256] bf16 tile (16B-chunk XOR by row&7)
__device__ __forceinline__ int asidx(int row, int col) {
  return row*256 + ((((col>>3) ^ (row & 7)))<<3) + (col&7);
}
// swizzled index into a [rows][32] bf16 scratch tile
__device__ __forceinline__ int scridx(int row, int col) {
  return row*32 + ((((col>>3) ^ ((row>>2)&3)))<<3) + (col&7);
}
// epilogue fp32 [64][256] staging: XOR bits 2-4 of f by row&7 (float4-safe)
__device__ __forceinline__ int epidx(int row, int f) {
  return row*256 + (f ^ ((row & 7) << 2));
}

struct WSrc { const float* p[8]; };

// fp32 [*,256,256] (f-major) -> bf16 WT[n=g][k=f] with the chunk XOR swizzle
// baked in, so a LINEAR global_load_lds stage yields the swizzled LDS layout.
__global__ __launch_bounds__(256) void prep_weights(WSrc s, ushort* wq, ushort* wo) {
  int mm = blockIdx.x >> 6;          // 0..15: axis*4 + {0,1,2:qkv mats, 3:wo}
  int t  = blockIdx.x & 63;
  int a = mm >> 2, sub = mm & 3;
  const float* src = (sub < 3) ? (s.p[a*2] + sub*65536) : s.p[a*2+1];
  ushort*      dst = (sub < 3) ? (wq + (a*3 + sub)*65536) : (wo + a*65536);
  int gt = (t >> 3) * 32, ft = (t & 7) * 32;
  __shared__ float tile[32][33];
  int lx = threadIdx.x & 31, ly = threadIdx.x >> 5;
#pragma unroll
  for (int i = 0; i < 4; i++)
    tile[ly + i*8][lx] = src[(ft + ly + i*8)*256 + gt + lx];
  __syncthreads();
#pragma unroll
  for (int i = 0; i < 4; i++) {
    int n = gt + ly + i*8, col = ft + lx;
    dst[asidx(n, col)] = f2bf(tile[lx][ly + i*8]);
  }
}

// 64-token blocks (1024 of them)
template<int AXIS>
__device__ __forceinline__ int token_index(int blk, int row) {
  if (AXIS == 0) {                       // temporal: 8 seqs/block of len 8
    int seq = blk*8 + (row >> 3);
    int t = row & 7;
    int b = seq >> 12, n = seq & 4095;
    return (b*8 + t)*4096 + n;
  } else {                               // spatial: 4 seqs/block of len 16
    int sid = blk*4 + (row >> 4);
    int bt = sid >> 8, lo = sid & 255, r = row & 15;
    if (AXIS == 1) { int hh = lo >> 4, ww = lo & 15; return bt*4096 + r*256 + hh*16 + ww; }
    if (AXIS == 2) { int dd = lo >> 4, ww = lo & 15; return bt*4096 + dd*256 + r*16 + ww; }
    { int dd = lo >> 4, hh = lo & 15; return bt*4096 + dd*256 + hh*16 + r; }
  }
}

// LDS-write publication fence (raw s_barrier does NOT drain ds ops).
#define PUB_BARRIER() do { \
    __builtin_amdgcn_sched_barrier(0); \
    asm volatile("s_waitcnt lgkmcnt(0)" ::: "memory"); \
    __builtin_amdgcn_sched_barrier(0); \
    __builtin_amdgcn_s_barrier(); \
    __builtin_amdgcn_sched_barrier(0); } while (0)

template<int AXIS>
__global__ __launch_bounds__(256, 2) void axial_pass(
    const float* __restrict__ x0, const ushort* __restrict__ xb,
    const ushort* __restrict__ wqkvT, const float* __restrict__ bqkv,
    const ushort* __restrict__ woT, const float* __restrict__ bo,
    float* __restrict__ out, ushort* __restrict__ x1b) {

  // 80 KB total (2 blocks/CU). Byte layout:
  //   [0,16K)  Wb0    [16K,32K) Wb1      (double-buffered weight stages)
  //   [32K,64K) AsT   (X stage -> per-head attn-out -> epilogue alias)
  //   [64K,80K) Scr   (4 packets x 4KB: Q 1K | K/P 1K | Vt 2K)
  // Epilogue Fep fp32[64][256] = 64KB aliases Wb0+Wb1+AsT.
  __shared__ ushort smem[40960];
  ushort* Wb0 = smem;
  ushort* Wb1 = smem + 8192;
  ushort* AsT = smem + 16384;
  ushort* Scr = smem + 32768;

  const int tid = threadIdx.x, blk = blockIdx.x;
  const int wv = tid >> 6, lane = tid & 63, llo = lane & 15, lhi = lane >> 4;
  const int rg = wv >> 1, ch = wv & 1;   // row-group (32 rows), n-half (16 cols)
  const f32x4 fzero = {0.f, 0.f, 0.f, 0.f};
  const s16x8 szero = {0,0,0,0,0,0,0,0};

  auto issue_stage = [&](int s) {
    const ushort* src = (s < 24) ? (wqkvT + (s % 3)*65536 + (s / 3)*8192)
                                 : (woT + (s - 24)*8192);
    const ushort* g = src + wv*2048 + lane*8;
    ushort* l = ((s & 1) ? Wb1 : Wb0) + wv*2048;
#pragma unroll
    for (int i = 0; i < 4; i++) glds16(g + i*512, l + i*512);
  };

  // Single barrier per stage, collective order (round-7-proven): drain own
  // vmcnt+lgkm BEFORE the barrier, issue the next stage AFTER it.
#define STAGE_SYNC(sn) do { \
    __builtin_amdgcn_sched_barrier(0); \
    asm volatile("s_waitcnt vmcnt(0) lgkmcnt(0)" ::: "memory"); \
    __builtin_amdgcn_sched_barrier(0); \
    __builtin_amdgcn_s_barrier(); \
    __builtin_amdgcn_sched_barrier(0); \
    if ((sn) < 32) issue_stage(sn); \
  } while (0)

  issue_stage(0);   // stage-0 weights load under the X staging below

  // ---- stage X tile into AsT (swizzled) ----
  {
    int row = tid >> 2, q = tid & 3;
    int tok = token_index<AXIS>(blk, row);
    if (AXIS == 0) {
      const float4* s4 = (const float4*)(x0 + (size_t)tok*256 + q*64);
#pragma unroll
      for (int c2 = 0; c2 < 8; c2++) {
        float4 v0 = s4[c2*2], v1 = s4[c2*2 + 1];
        s16x8 o;
        o[0] = (short)f2bf(v0.x); o[1] = (short)f2bf(v0.y);
        o[2] = (short)f2bf(v0.z); o[3] = (short)f2bf(v0.w);
        o[4] = (short)f2bf(v1.x); o[5] = (short)f2bf(v1.y);
        o[6] = (short)f2bf(v1.z); o[7] = (short)f2bf(v1.w);
        *(s16x8*)(AsT + asidx(row, (q*8 + c2)*8)) = o;
      }
    } else {
      const s16x8* s8 = (const s16x8*)(xb + (size_t)tok*256 + q*64);
#pragma unroll
      for (int c2 = 0; c2 < 8; c2++)
        *(s16x8*)(AsT + asidx(row, (q*8 + c2)*8)) = s8[c2];
    }
  }
  // zero own packet's V^T k-pad (cols 16..31) once
  {
    ushort* Vtw = Scr + wv*2048 + 1024;
    *(s16x8*)(Vtw + scridx(lane >> 1, 16 + (lane & 1)*8)) = szero;
  }
  __syncthreads();   // X + pad + stage-0 glds all published

  // ---- A-fragments: 2 row-groups (32 rows) per wave, in registers ----
  s16x8 af[2][8];
#pragma unroll
  for (int g = 0; g < 2; g++)
#pragma unroll
    for (int ks = 0; ks < 8; ks++)
      af[g][ks] = *(const s16x8*)(AsT + asidx(rg*32 + g*16 + llo, (ks*4 + lhi)*8));

  // projection: 8 B-reads feed 16 MFMAs (2 independent chains)
  auto proj2 = [&](int sb, f32x4& c0, f32x4& c1) {
    const ushort* buf = sb ? Wb1 : Wb0;
    __builtin_amdgcn_s_setprio(1);
#pragma unroll
    for (int ks = 0; ks < 8; ks++) {
      s16x8 bv = *(const s16x8*)(buf + asidx(ch*16 + llo, (ks*4 + lhi)*8));
      c0 = __builtin_amdgcn_mfma_f32_16x16x32_bf16(af[0][ks], bv, c0, 0, 0, 0);
      c1 = __builtin_amdgcn_mfma_f32_16x16x32_bf16(af[1][ks], bv, c1, 0, 0, 0);
    }
    __builtin_amdgcn_s_setprio(0);
  };

  // ================= head loop: stages 3h (Q), 3h+1 (K), 3h+2 (V) ==========
#pragma unroll 1
  for (int h = 0; h < 8; h++) {
    // ---- Q ----
    STAGE_SYNC(3*h + 1);
    {
      f32x4 c0 = fzero, c1 = fzero;
      proj2((3*h) & 1, c0, c1);
      float bi = bqkv[h*32 + ch*16 + llo];
      ushort* q0 = Scr + (rg*2 + 0)*2048;
      ushort* q1 = Scr + (rg*2 + 1)*2048;
#pragma unroll
      for (int r = 0; r < 4; r++) {
        q0[scridx(lhi*4 + r, ch*16 + llo)] = f2bf(c0[r] + bi);
        q1[scridx(lhi*4 + r, ch*16 + llo)] = f2bf(c1[r] + bi);
      }
    }
    // ---- K ----
    STAGE_SYNC(3*h + 2);
    {
      f32x4 c0 = fzero, c1 = fzero;
      proj2((3*h + 1) & 1, c0, c1);
      float bi = bqkv[256 + h*32 + ch*16 + llo];
      ushort* k0 = Scr + (rg*2 + 0)*2048 + 512;
      ushort* k1 = Scr + (rg*2 + 1)*2048 + 512;
#pragma unroll
      for (int r = 0; r < 4; r++) {
        k0[scridx(lhi*4 + r, ch*16 + llo)] = f2bf(c0[r] + bi);
        k1[scridx(lhi*4 + r, ch*16 + llo)] = f2bf(c1[r] + bi);
      }
    }
    // ---- V (stored transposed [d][t] into each packet's Vt) ----
    STAGE_SYNC(3*h + 3);
    {
      f32x4 c0 = fzero, c1 = fzero;
      proj2((3*h + 2) & 1, c0, c1);
      float bi = bqkv[512 + h*32 + ch*16 + llo];
      ushort* v0 = Scr + (rg*2 + 0)*2048 + 1024;
      ushort* v1 = Scr + (rg*2 + 1)*2048 + 1024;
#pragma unroll
      for (int r = 0; r < 4; r++) {
        v0[scridx(ch*16 + llo, lhi*4 + r)] = f2bf(c0[r] + bi);
        v1[scridx(ch*16 + llo, lhi*4 + r)] = f2bf(c1[r] + bi);
      }
    }
    PUB_BARRIER();   // Q,K,V for all packets published

    // ---- attention: wave owns packet wv; all LDS below same-wave ----
    {
      ushort* S = Scr + wv*2048;
      s16x8 aq = *(const s16x8*)(S + scridx(llo, lhi*8));
      s16x8 bk = *(const s16x8*)(S + 512 + scridx(llo, lhi*8));
      f32x4 sc = __builtin_amdgcn_mfma_f32_16x16x32_bf16(aq, bk, fzero, 0, 0, 0);
#pragma unroll
      for (int r = 0; r < 4; r++) {
        float sv = sc[r] * 0.17677669529663689f;
        if (AXIS == 0) {   // two packed length-8 seqs: block-diagonal mask
          int srow = lhi*4 + r;
          if ((srow >> 3) != (llo >> 3)) sv = -1e30f;
        }
        float mx = sv;
        mx = fmaxf(mx, __shfl_xor(mx, 1));
        mx = fmaxf(mx, __shfl_xor(mx, 2));
        mx = fmaxf(mx, __shfl_xor(mx, 4));
        mx = fmaxf(mx, __shfl_xor(mx, 8));
        float e = __expf(sv - mx);
        float sm = e;
        sm += __shfl_xor(sm, 1);
        sm += __shfl_xor(sm, 2);
        sm += __shfl_xor(sm, 4);
        sm += __shfl_xor(sm, 8);
        (S + 512)[scridx(lhi*4 + r, llo)] = f2bf(e * __builtin_amdgcn_rcpf(sm)); // P over K
      }
      // PV (P k-pad garbage x V^T zero-pad = 0); same-wave in-order LDS
      s16x8 ap  = *(const s16x8*)(S + 512 + scridx(llo, lhi*8));
      s16x8 bv0 = *(const s16x8*)(S + 1024 + scridx(llo, lhi*8));
      s16x8 bv1 = *(const s16x8*)(S + 1024 + scridx(16 + llo, lhi*8));
      f32x4 o0 = __builtin_amdgcn_mfma_f32_16x16x32_bf16(ap, bv0, fzero, 0, 0, 0);
      f32x4 o1 = __builtin_amdgcn_mfma_f32_16x16x32_bf16(ap, bv1, fzero, 0, 0, 0);
#pragma unroll
      for (int r = 0; r < 4; r++) {
        AsT[asidx(wv*16 + lhi*4 + r, h*32 + llo)]      = f2bf(o0[r]);
        AsT[asidx(wv*16 + lhi*4 + r, h*32 + 16 + llo)] = f2bf(o1[r]);
      }
    }
    // next head's Q-stage barrier orders: our attn reads drained at its
    // lgkm-before-barrier; producers' overwrites happen after it.
  }

  PUB_BARRIER();   // attn-out tile (AsT) published for cross-wave af reload

  // ---- reload A-fragments = attn outputs for own 32 rows ----
#pragma unroll
  for (int g = 0; g < 2; g++)
#pragma unroll
    for (int ks = 0; ks < 8; ks++)
      af[g][ks] = *(const s16x8*)(AsT + asidx(rg*32 + g*16 + llo, (ks*4 + lhi)*8));

  // ================= out-proj: stages 24..31, acc += A @ Wo =================
  f32x4 acc[16];
#pragma unroll
  for (int i = 0; i < 16; i++) acc[i] = fzero;
#pragma unroll 1
  for (int st = 0; st < 8; st++) {
    STAGE_SYNC(25 + st);
    const ushort* buf = (st & 1) ? Wb1 : Wb0;
    __builtin_amdgcn_s_setprio(1);
#pragma unroll
    for (int ks = 0; ks < 8; ks++) {
      s16x8 bv = *(const s16x8*)(buf + asidx(ch*16 + llo, (ks*4 + lhi)*8));
      acc[st*2]   = __builtin_amdgcn_mfma_f32_16x16x32_bf16(af[0][ks], bv, acc[st*2],   0, 0, 0);
      acc[st*2+1] = __builtin_amdgcn_mfma_f32_16x16x32_bf16(af[1][ks], bv, acc[st*2+1], 0, 0, 0);
    }
    __builtin_amdgcn_s_setprio(0);
  }

  // ======== vectorized epilogue: transpose acc through LDS, full-line RMW ===
  float* Fep = (float*)smem;   // fp32 [64][256] over Wb0+Wb1+AsT (all dead)
  PUB_BARRIER();               // all waves done reading Wbuf/AsT
#pragma unroll
  for (int st = 0; st < 8; st++) {
#pragma unroll
    for (int g = 0; g < 2; g++) {
#pragma unroll
      for (int r = 0; r < 4; r++) {
        int row = rg*32 + g*16 + lhi*4 + r;
        Fep[epidx(row, st*32 + ch*16 + llo)] = acc[st*2 + g][r];
      }
    }
  }
  PUB_BARRIER();   // acc tile published
  {
    int rbase = tid >> 3, g = tid & 7;
#pragma unroll 1
    for (int step = 0; step < 2; step++) {
      int row = rbase + step*32;
      int tok = token_index<AXIS>(blk, row);
      size_t base = (size_t)tok*256;
#pragma unroll
      for (int i = 0; i < 8; i++) {
        int f = i*32 + g*4;
        float4 v = *(float4*)&Fep[epidx(row, f)];
        float4 b = *(const float4*)&bo[f];
        v.x += b.x; v.y += b.y; v.z += b.z; v.w += b.w;
        if (AXIS == 0) {
          float4 x = *(const float4*)&x0[base + f];
          v.x += x.x; v.y += x.y; v.z += x.z; v.w += x.w;
          *(float4*)&out[base + f] = v;             // x1 (fp32)
          ushort4 p; p.x = f2bf(v.x); p.y = f2bf(v.y);
          p.z = f2bf(v.z); p.w = f2bf(v.w);
          *(ushort4*)&x1b[base + f] = p;            // x1 (bf16)
        } else {
          float4 o = *(float4*)&out[base + f];
          o.x += v.x; o.y += v.y; o.z += v.z; o.w += v.w;
          *(float4*)&out[base + f] = o;             // accumulate axis contribution
        }
      }
    }
  }
#undef STAGE_SYNC
}

extern "C" void kernel_launch(void* const* d_in, const int* in_sizes, int n_in,
                              void* d_out, int out_size, void* d_ws, size_t ws_size,
                              hipStream_t stream) {
  const float* x = (const float*)d_in[0];
  ushort* wq  = (ushort*)d_ws;                 // 4*3*65536 bf16
  ushort* wo  = wq + 4*3*65536;                // 4*65536 bf16
  ushort* x1b = wo + 4*65536;                  // 65536*256 bf16
  float* out = (float*)d_out;

  WSrc wsrc;
  wsrc.p[0] = (const float*)d_in[1];  wsrc.p[1] = (const float*)d_in[3];
  wsrc.p[2] = (const float*)d_in[5];  wsrc.p[3] = (const float*)d_in[7];
  wsrc.p[4] = (const float*)d_in[9];  wsrc.p[5] = (const float*)d_in[11];
  wsrc.p[6] = (const float*)d_in[13]; wsrc.p[7] = (const float*)d_in[15];
  prep_weights<<<dim3(1024), dim3(256), 0, stream>>>(wsrc, wq, wo);

  const float* bq_t = (const float*)d_in[2];  const float* bo_t = (const float*)d_in[4];
  const float* bq_d = (const float*)d_in[6];  const float* bo_d = (const float*)d_in[8];
  const float* bq_h = (const float*)d_in[10]; const float* bo_h = (const float*)d_in[12];
  const float* bq_w = (const float*)d_in[14]; const float* bo_w = (const float*)d_in[16];

  axial_pass<0><<<dim3(1024), dim3(256), 0, stream>>>(x, nullptr, wq + 0*3*65536, bq_t, wo + 0*65536, bo_t, out, x1b);
  axial_pass<1><<<dim3(1024), dim3(256), 0, stream>>>(nullptr, x1b, wq + 1*3*65536, bq_d, wo + 1*65536, bo_d, out, nullptr);
  axial_pass<2><<<dim3(1024), dim3(256), 0, stream>>>(nullptr, x1b, wq + 2*3*65536, bq_h, wo + 2*65536, bo_h, out, nullptr);
  axial_pass<3><<<dim3(1024), dim3(256), 0, stream>>>(nullptr, x1b, wq + 3*3*65536, bq_w, wo + 3*65536, bo_w, out, nullptr);
}

// Round 12
// 351.008 us; speedup vs baseline: 1.4869x; 1.3180x over previous
//
#include <hip/hip_runtime.h>

typedef __attribute__((ext_vector_type(4))) float f32x4;
typedef __attribute__((ext_vector_type(8))) short s16x8;

__device__ __forceinline__ ushort f2bf(float f) {
  union { float f; uint u; } v; v.f = f;
  uint r = v.u + 0x7fffu + ((v.u >> 16) & 1u);
  return (ushort)(r >> 16);
}

__device__ __forceinline__ void glds16(const void* g, void* l) {
  __builtin_amdgcn_global_load_lds(
      (const __attribute__((address_space(1))) uint*)g,
      (__attribute__((address_space(3))) uint*)l, 16, 0, 0);
}

// swizzled index into a [rows][256] bf16 tile (16B-chunk XOR by row&7)
__device__ __forceinline__ int asidx(int row, int col) {
  return row*256 + ((((col>>3) ^ (row & 7)))<<3) + (col&7);
}
// swizzled index into a [rows][32] bf16 scratch tile
__device__ __forceinline__ int scridx(int row, int col) {
  return row*32 + ((((col>>3) ^ ((row>>2)&3)))<<3) + (col&7);
}
// epilogue fp32 [64][256] staging: XOR bits 2-4 of f by row&7 (float4-safe)
__device__ __forceinline__ int epidx(int row, int f) {
  return row*256 + (f ^ ((row & 7) << 2));
}

struct WSrc { const float* p[8]; };

// fp32 [*,256,256] (f-major) -> bf16 WT[n=g][k=f] with the chunk XOR swizzle
// baked in, so a LINEAR global_load_lds stage yields the swizzled LDS layout.
__global__ __launch_bounds__(256) void prep_weights(WSrc s, ushort* wq, ushort* wo) {
  int mm = blockIdx.x >> 6;          // 0..15: axis*4 + {0,1,2:qkv mats, 3:wo}
  int t  = blockIdx.x & 63;
  int a = mm >> 2, sub = mm & 3;
  const float* src = (sub < 3) ? (s.p[a*2] + sub*65536) : s.p[a*2+1];
  ushort*      dst = (sub < 3) ? (wq + (a*3 + sub)*65536) : (wo + a*65536);
  int gt = (t >> 3) * 32, ft = (t & 7) * 32;
  __shared__ float tile[32][33];
  int lx = threadIdx.x & 31, ly = threadIdx.x >> 5;
#pragma unroll
  for (int i = 0; i < 4; i++)
    tile[ly + i*8][lx] = src[(ft + ly + i*8)*256 + gt + lx];
  __syncthreads();
#pragma unroll
  for (int i = 0; i < 4; i++) {
    int n = gt + ly + i*8, col = ft + lx;
    dst[asidx(n, col)] = f2bf(tile[lx][ly + i*8]);
  }
}

// 64-token blocks (1024 of them)
template<int AXIS>
__device__ __forceinline__ int token_index(int blk, int row) {
  if (AXIS == 0) {                       // temporal: 8 seqs/block of len 8
    int seq = blk*8 + (row >> 3);
    int t = row & 7;
    int b = seq >> 12, n = seq & 4095;
    return (b*8 + t)*4096 + n;
  } else {                               // spatial: 4 seqs/block of len 16
    int sid = blk*4 + (row >> 4);
    int bt = sid >> 8, lo = sid & 255, r = row & 15;
    if (AXIS == 1) { int hh = lo >> 4, ww = lo & 15; return bt*4096 + r*256 + hh*16 + ww; }
    if (AXIS == 2) { int dd = lo >> 4, ww = lo & 15; return bt*4096 + dd*256 + r*16 + ww; }
    { int dd = lo >> 4, hh = lo & 15; return bt*4096 + dd*256 + hh*16 + r; }
  }
}

// LDS-write publication fence (raw s_barrier does NOT drain ds ops).
#define PUB_BARRIER() do { \
    __builtin_amdgcn_sched_barrier(0); \
    asm volatile("s_waitcnt lgkmcnt(0)" ::: "memory"); \
    __builtin_amdgcn_sched_barrier(0); \
    __builtin_amdgcn_s_barrier(); \
    __builtin_amdgcn_sched_barrier(0); } while (0)

template<int AXIS>
__global__ __launch_bounds__(256, 2) void axial_pass(
    const float* __restrict__ x0, const ushort* __restrict__ xb,
    const ushort* __restrict__ wqkvT, const float* __restrict__ bqkv,
    const ushort* __restrict__ woT, const float* __restrict__ bo,
    float* __restrict__ out, ushort* __restrict__ x1b) {

  // 80 KB total (2 blocks/CU). Byte layout:
  //   [0,16K)  Wb0    [16K,32K) Wb1      (double-buffered weight stages)
  //   [32K,64K) AsT   (X stage -> per-head attn-out -> epilogue alias)
  //   [64K,80K) Scr   (4 packets x 4KB: Q 1K | K/P 1K | Vt 2K)
  // Epilogue Fep fp32[64][256] = 64KB aliases Wb0+Wb1+AsT.
  __shared__ ushort smem[40960];
  ushort* Wb0 = smem;
  ushort* Wb1 = smem + 8192;
  ushort* AsT = smem + 16384;
  ushort* Scr = smem + 32768;

  const int tid = threadIdx.x, blk = blockIdx.x;
  const int wv = tid >> 6, lane = tid & 63, llo = lane & 15, lhi = lane >> 4;
  const int rg = wv >> 1, ch = wv & 1;   // row-group (32 rows), n-half (16 cols)
  const f32x4 fzero = {0.f, 0.f, 0.f, 0.f};
  const s16x8 szero = {0,0,0,0,0,0,0,0};

  auto issue_stage = [&](int s) {
    const ushort* src = (s < 24) ? (wqkvT + (s % 3)*65536 + (s / 3)*8192)
                                 : (woT + (s - 24)*8192);
    const ushort* g = src + wv*2048 + lane*8;
    ushort* l = ((s & 1) ? Wb1 : Wb0) + wv*2048;
#pragma unroll
    for (int i = 0; i < 4; i++) glds16(g + i*512, l + i*512);
  };

  // Single barrier per stage, collective order (round-7-proven): drain own
  // vmcnt+lgkm BEFORE the barrier, issue the next stage AFTER it.
#define STAGE_SYNC(sn) do { \
    __builtin_amdgcn_sched_barrier(0); \
    asm volatile("s_waitcnt vmcnt(0) lgkmcnt(0)" ::: "memory"); \
    __builtin_amdgcn_sched_barrier(0); \
    __builtin_amdgcn_s_barrier(); \
    __builtin_amdgcn_sched_barrier(0); \
    if ((sn) < 32) issue_stage(sn); \
  } while (0)

  issue_stage(0);   // stage-0 weights load under the X staging below

  // ---- stage X tile into AsT (swizzled) ----
  {
    int row = tid >> 2, q = tid & 3;
    int tok = token_index<AXIS>(blk, row);
    if (AXIS == 0) {
      const float4* s4 = (const float4*)(x0 + (size_t)tok*256 + q*64);
#pragma unroll
      for (int c2 = 0; c2 < 8; c2++) {
        float4 v0 = s4[c2*2], v1 = s4[c2*2 + 1];
        s16x8 o;
        o[0] = (short)f2bf(v0.x); o[1] = (short)f2bf(v0.y);
        o[2] = (short)f2bf(v0.z); o[3] = (short)f2bf(v0.w);
        o[4] = (short)f2bf(v1.x); o[5] = (short)f2bf(v1.y);
        o[6] = (short)f2bf(v1.z); o[7] = (short)f2bf(v1.w);
        *(s16x8*)(AsT + asidx(row, (q*8 + c2)*8)) = o;
      }
    } else {
      const s16x8* s8 = (const s16x8*)(xb + (size_t)tok*256 + q*64);
#pragma unroll
      for (int c2 = 0; c2 < 8; c2++)
        *(s16x8*)(AsT + asidx(row, (q*8 + c2)*8)) = s8[c2];
    }
  }
  // zero own packet's V^T k-pad (cols 16..31) once
  {
    ushort* Vtw = Scr + wv*2048 + 1024;
    *(s16x8*)(Vtw + scridx(lane >> 1, 16 + (lane & 1)*8)) = szero;
  }
  __syncthreads();   // X + pad + stage-0 glds all published

  // ---- A-fragments: 2 row-groups (32 rows) per wave, in registers ----
  s16x8 af[2][8];
#pragma unroll
  for (int g = 0; g < 2; g++)
#pragma unroll
    for (int ks = 0; ks < 8; ks++)
      af[g][ks] = *(const s16x8*)(AsT + asidx(rg*32 + g*16 + llo, (ks*4 + lhi)*8));

  // projection: 8 B-reads feed 16 MFMAs (2 independent chains)
  auto proj2 = [&](int sb, f32x4& c0, f32x4& c1) {
    const ushort* buf = sb ? Wb1 : Wb0;
    __builtin_amdgcn_s_setprio(1);
#pragma unroll
    for (int ks = 0; ks < 8; ks++) {
      s16x8 bv = *(const s16x8*)(buf + asidx(ch*16 + llo, (ks*4 + lhi)*8));
      c0 = __builtin_amdgcn_mfma_f32_16x16x32_bf16(af[0][ks], bv, c0, 0, 0, 0);
      c1 = __builtin_amdgcn_mfma_f32_16x16x32_bf16(af[1][ks], bv, c1, 0, 0, 0);
    }
    __builtin_amdgcn_s_setprio(0);
  };

  // ================= head loop: stages 3h (Q), 3h+1 (K), 3h+2 (V) ==========
#pragma unroll 1
  for (int h = 0; h < 8; h++) {
    // ---- Q ----
    STAGE_SYNC(3*h + 1);
    {
      f32x4 c0 = fzero, c1 = fzero;
      proj2((3*h) & 1, c0, c1);
      float bi = bqkv[h*32 + ch*16 + llo];
      ushort* q0 = Scr + (rg*2 + 0)*2048;
      ushort* q1 = Scr + (rg*2 + 1)*2048;
#pragma unroll
      for (int r = 0; r < 4; r++) {
        q0[scridx(lhi*4 + r, ch*16 + llo)] = f2bf(c0[r] + bi);
        q1[scridx(lhi*4 + r, ch*16 + llo)] = f2bf(c1[r] + bi);
      }
    }
    // ---- K ----
    STAGE_SYNC(3*h + 2);
    {
      f32x4 c0 = fzero, c1 = fzero;
      proj2((3*h + 1) & 1, c0, c1);
      float bi = bqkv[256 + h*32 + ch*16 + llo];
      ushort* k0 = Scr + (rg*2 + 0)*2048 + 512;
      ushort* k1 = Scr + (rg*2 + 1)*2048 + 512;
#pragma unroll
      for (int r = 0; r < 4; r++) {
        k0[scridx(lhi*4 + r, ch*16 + llo)] = f2bf(c0[r] + bi);
        k1[scridx(lhi*4 + r, ch*16 + llo)] = f2bf(c1[r] + bi);
      }
    }
    // ---- V (stored transposed [d][t] into each packet's Vt) ----
    STAGE_SYNC(3*h + 3);
    {
      f32x4 c0 = fzero, c1 = fzero;
      proj2((3*h + 2) & 1, c0, c1);
      float bi = bqkv[512 + h*32 + ch*16 + llo];
      ushort* v0 = Scr + (rg*2 + 0)*2048 + 1024;
      ushort* v1 = Scr + (rg*2 + 1)*2048 + 1024;
#pragma unroll
      for (int r = 0; r < 4; r++) {
        v0[scridx(ch*16 + llo, lhi*4 + r)] = f2bf(c0[r] + bi);
        v1[scridx(ch*16 + llo, lhi*4 + r)] = f2bf(c1[r] + bi);
      }
    }
    PUB_BARRIER();   // Q,K,V for all packets published

    // ---- attention: wave owns packet wv; all LDS below same-wave ----
    {
      ushort* S = Scr + wv*2048;
      s16x8 aq = *(const s16x8*)(S + scridx(llo, lhi*8));
      s16x8 bk = *(const s16x8*)(S + 512 + scridx(llo, lhi*8));
      f32x4 sc = __builtin_amdgcn_mfma_f32_16x16x32_bf16(aq, bk, fzero, 0, 0, 0);
#pragma unroll
      for (int r = 0; r < 4; r++) {
        float sv = sc[r] * 0.17677669529663689f;
        if (AXIS == 0) {   // two packed length-8 seqs: block-diagonal mask
          int srow = lhi*4 + r;
          if ((srow >> 3) != (llo >> 3)) sv = -1e30f;
        }
        float mx = sv;
        mx = fmaxf(mx, __shfl_xor(mx, 1));
        mx = fmaxf(mx, __shfl_xor(mx, 2));
        mx = fmaxf(mx, __shfl_xor(mx, 4));
        mx = fmaxf(mx, __shfl_xor(mx, 8));
        float e = __expf(sv - mx);
        float sm = e;
        sm += __shfl_xor(sm, 1);
        sm += __shfl_xor(sm, 2);
        sm += __shfl_xor(sm, 4);
        sm += __shfl_xor(sm, 8);
        (S + 512)[scridx(lhi*4 + r, llo)] = f2bf(e * __builtin_amdgcn_rcpf(sm)); // P over K
      }
      // PV (P k-pad garbage x V^T zero-pad = 0); same-wave in-order LDS
      s16x8 ap  = *(const s16x8*)(S + 512 + scridx(llo, lhi*8));
      s16x8 bv0 = *(const s16x8*)(S + 1024 + scridx(llo, lhi*8));
      s16x8 bv1 = *(const s16x8*)(S + 1024 + scridx(16 + llo, lhi*8));
      f32x4 o0 = __builtin_amdgcn_mfma_f32_16x16x32_bf16(ap, bv0, fzero, 0, 0, 0);
      f32x4 o1 = __builtin_amdgcn_mfma_f32_16x16x32_bf16(ap, bv1, fzero, 0, 0, 0);
#pragma unroll
      for (int r = 0; r < 4; r++) {
        AsT[asidx(wv*16 + lhi*4 + r, h*32 + llo)]      = f2bf(o0[r]);
        AsT[asidx(wv*16 + lhi*4 + r, h*32 + 16 + llo)] = f2bf(o1[r]);
      }
    }
    // next head's Q-stage barrier orders: our attn reads drained at its
    // lgkm-before-barrier; producers' overwrites happen after it.
  }

  PUB_BARRIER();   // attn-out tile (AsT) published for cross-wave af reload

  // ---- reload A-fragments = attn outputs for own 32 rows ----
#pragma unroll
  for (int g = 0; g < 2; g++)
#pragma unroll
    for (int ks = 0; ks < 8; ks++)
      af[g][ks] = *(const s16x8*)(AsT + asidx(rg*32 + g*16 + llo, (ks*4 + lhi)*8));

  // ================= out-proj: stages 24..31, acc += A @ Wo =================
  // FULLY UNROLLED so every acc index is compile-time constant (rule #20):
  // runtime-indexed acc[] was allocated in scratch in r11 -> ~130MB/pass of
  // HBM spill traffic (WRITE 208MB, VGPR_Count 88). Static -> registers.
  f32x4 acc[16];
#pragma unroll
  for (int i = 0; i < 16; i++) acc[i] = fzero;
#pragma unroll
  for (int st = 0; st < 8; st++) {
    STAGE_SYNC(25 + st);
    const ushort* buf = (st & 1) ? Wb1 : Wb0;
    __builtin_amdgcn_s_setprio(1);
#pragma unroll
    for (int ks = 0; ks < 8; ks++) {
      s16x8 bv = *(const s16x8*)(buf + asidx(ch*16 + llo, (ks*4 + lhi)*8));
      acc[st*2]   = __builtin_amdgcn_mfma_f32_16x16x32_bf16(af[0][ks], bv, acc[st*2],   0, 0, 0);
      acc[st*2+1] = __builtin_amdgcn_mfma_f32_16x16x32_bf16(af[1][ks], bv, acc[st*2+1], 0, 0, 0);
    }
    __builtin_amdgcn_s_setprio(0);
  }

  // ======== vectorized epilogue: transpose acc through LDS, full-line RMW ===
  float* Fep = (float*)smem;   // fp32 [64][256] over Wb0+Wb1+AsT (all dead)
  PUB_BARRIER();               // all waves done reading Wbuf/AsT
#pragma unroll
  for (int st = 0; st < 8; st++) {
#pragma unroll
    for (int g = 0; g < 2; g++) {
#pragma unroll
      for (int r = 0; r < 4; r++) {
        int row = rg*32 + g*16 + lhi*4 + r;
        Fep[epidx(row, st*32 + ch*16 + llo)] = acc[st*2 + g][r];
      }
    }
  }
  PUB_BARRIER();   // acc tile published
  {
    int rbase = tid >> 3, g = tid & 7;
#pragma unroll 1
    for (int step = 0; step < 2; step++) {
      int row = rbase + step*32;
      int tok = token_index<AXIS>(blk, row);
      size_t base = (size_t)tok*256;
#pragma unroll
      for (int i = 0; i < 8; i++) {
        int f = i*32 + g*4;
        float4 v = *(float4*)&Fep[epidx(row, f)];
        float4 b = *(const float4*)&bo[f];
        v.x += b.x; v.y += b.y; v.z += b.z; v.w += b.w;
        if (AXIS == 0) {
          float4 x = *(const float4*)&x0[base + f];
          v.x += x.x; v.y += x.y; v.z += x.z; v.w += x.w;
          *(float4*)&out[base + f] = v;             // x1 (fp32)
          ushort4 p; p.x = f2bf(v.x); p.y = f2bf(v.y);
          p.z = f2bf(v.z); p.w = f2bf(v.w);
          *(ushort4*)&x1b[base + f] = p;            // x1 (bf16)
        } else {
          float4 o = *(float4*)&out[base + f];
          o.x += v.x; o.y += v.y; o.z += v.z; o.w += v.w;
          *(float4*)&out[base + f] = o;             // accumulate axis contribution
        }
      }
    }
  }
#undef STAGE_SYNC
}

extern "C" void kernel_launch(void* const* d_in, const int* in_sizes, int n_in,
                              void* d_out, int out_size, void* d_ws, size_t ws_size,
                              hipStream_t stream) {
  const float* x = (const float*)d_in[0];
  ushort* wq  = (ushort*)d_ws;                 // 4*3*65536 bf16
  ushort* wo  = wq + 4*3*65536;                // 4*65536 bf16
  ushort* x1b = wo + 4*65536;                  // 65536*256 bf16
  float* out = (float*)d_out;

  WSrc wsrc;
  wsrc.p[0] = (const float*)d_in[1];  wsrc.p[1] = (const float*)d_in[3];
  wsrc.p[2] = (const float*)d_in[5];  wsrc.p[3] = (const float*)d_in[7];
  wsrc.p[4] = (const float*)d_in[9];  wsrc.p[5] = (const float*)d_in[11];
  wsrc.p[6] = (const float*)d_in[13]; wsrc.p[7] = (const float*)d_in[15];
  prep_weights<<<dim3(1024), dim3(256), 0, stream>>>(wsrc, wq, wo);

  const float* bq_t = (const float*)d_in[2];  const float* bo_t = (const float*)d_in[4];
  const float* bq_d = (const float*)d_in[6];  const float* bo_d = (const float*)d_in[8];
  const float* bq_h = (const float*)d_in[10]; const float* bo_h = (const float*)d_in[12];
  const float* bq_w = (const float*)d_in[14]; const float* bo_w = (const float*)d_in[16];

  axial_pass<0><<<dim3(1024), dim3(256), 0, stream>>>(x, nullptr, wq + 0*3*65536, bq_t, wo + 0*65536, bo_t, out, x1b);
  axial_pass<1><<<dim3(1024), dim3(256), 0, stream>>>(nullptr, x1b, wq + 1*3*65536, bq_d, wo + 1*65536, bo_d, out, nullptr);
  axial_pass<2><<<dim3(1024), dim3(256), 0, stream>>>(nullptr, x1b, wq + 2*3*65536, bq_h, wo + 2*65536, bo_h, out, nullptr);
  axial_pass<3><<<dim3(1024), dim3(256), 0, stream>>>(nullptr, x1b, wq + 3*3*65536, bq_w, wo + 3*65536, bo_w, out, nullptr);
}